// Round 18
// baseline (369.288 us; speedup 1.0000x reference)
//
#include <hip/hip_runtime.h>
#include <hip/hip_bf16.h>

// 2-layer LSTM (H=32, T=512, I=1) + FC(1) + ReLU, fused, SELF-ALIGNED
// single-wave layers. Tile permutation: tile t row rho = gate(rho&3) of
// unit 8*(rho>>2)+t  =>  after 8 MFMA tiles, lane (m,col) holds (i,f,g,o)
// of units 8m..8m+7 of batch col -- exactly its own next-step B-fragment.
// The recurrence closes IN-REGISTER: 8 CELLs -> 4 in-lane cvt_pk -> bf16x8
// -> next MFMA. No LDS, no swizzle, no barrier inside a layer.
// Block = 2 waves x 16 batches: w0 = all of layer 0 (8 MFMA/step, 8 cells/
// lane, ILP-8 trans chains), w1 = all of layer 1 (16 MFMA/step), lagging
// 4..7 steps behind an 8-deep LDS ring of h0 (1 b128 write/step; 4
// prefetched b128 reads per superstep). ONE barrier per 4 steps (128 vs
// R15's 512). Zero gate select; bias (+x for L0) in MFMA C-in; merged-rcp
// CELL (7 trans). Grid 256 x 128 threads -> 2 waves/CU, issue-saturated.

typedef __attribute__((ext_vector_type(8))) short bf16x8;
typedef __attribute__((ext_vector_type(4))) float f32x4;
typedef __attribute__((ext_vector_type(4))) int   i32x4;

#define HID 32
#define SEQ 512
#define L2E 1.4426950408889634f
#define LSTR 20   // ring row stride in dwords (16 used + 4 pad)

static __device__ __forceinline__ float fexp2(float x){ return __builtin_amdgcn_exp2f(x); }
static __device__ __forceinline__ float frcp (float x){ return __builtin_amdgcn_rcpf(x); }
static __device__ __forceinline__ short f2bf(float f){
  unsigned u = __builtin_bit_cast(unsigned, f);
  u = (u + 0x7fffu + ((u >> 16) & 1u)) >> 16;
  return (short)u;
}

// fused LSTM cell, merged-rcp form. Gates pre-scaled (i,f,o by -log2e;
// g by +2log2e):  I=e^-i, F=e^-f, O=e^-o, G=e^{2g}.
#define CELL(gi, gf, gg, go, cvr, hout) do {                         \
  const float I_ = fexp2(gi), G_ = fexp2(gg);                        \
  const float F_ = fexp2(gf), O_ = fexp2(go);                        \
  const float a_ = 1.f + I_, b_ = 1.f + G_, c_ = 1.f + F_;           \
  const float P1_ = a_ * b_;                                         \
  const float R_  = frcp(c_ * P1_);                                  \
  const float fv_ = P1_ * R_;                                        \
  const float ig_ = (G_ - 1.f) * (c_ * R_);                          \
  (cvr) = fmaf(fv_, (cvr), ig_);                                     \
  const float C2_ = fexp2((cvr) * (2.f * L2E));                      \
  (hout) = (C2_ - 1.f) * frcp((1.f + O_) * (1.f + C2_));             \
} while (0)

__global__ __launch_bounds__(128, 1) void lstm2_sa_kernel(
    const float* __restrict__ x,
    const float* __restrict__ Wih0, const float* __restrict__ Whh0,
    const float* __restrict__ bih0, const float* __restrict__ bhh0,
    const float* __restrict__ Wih1, const float* __restrict__ Whh1,
    const float* __restrict__ bih1, const float* __restrict__ bhh1,
    const float* __restrict__ Wfc, const float* __restrict__ bfc,
    float* __restrict__ out)
{
  const int tid = threadIdx.x;
  const int w   = tid >> 6;          // 0: layer-0 wave, 1: layer-1 wave
  const int l   = tid & 63;
  const int m   = l >> 4;            // k-group; owns units 8m..8m+7
  const int col = l & 15;            // batch slot (16 batches/block)
  const int batch = blockIdx.x * 16 + col;

  __shared__ int ring[8][16 * LSTR];   // h0 ring, 8 steps deep (~10 KiB)

  // ---- weights: tile t row rho = gate(rho&3) of unit 8*(rho>>2)+t.
  //      Lane supplies A row = col. Pre-scaled: i,f,o -> -log2e; g -> +2log2e.
  const float* Bi  = (w == 0) ? bih0 : bih1;
  const float* Bh  = (w == 0) ? bhh0 : bhh1;
  const int   gcol = col & 3;              // gate type this lane's A-row feeds
  const float scA  = (gcol == 2) ? (2.0f * L2E) : (-L2E);
  const int   ub   = 8 * (col >> 2);       // A-row unit base

  bf16x8 wfA[8], wfB[8];   // w0: wfA=Whh0; w1: wfA=Wih1, wfB=Whh1
  f32x4  cb[8];            // MFMA C-in: per-slot gate bias (pre-scaled)
  float  w0x[8][4];        // w0 only: sc * Wih0 for owned units
  float  wfc[8];           // w1 only: FC weights
  #pragma unroll
  for (int t = 0; t < 8; ++t) {
    const int ga = gcol * 32 + ub + t;     // gate row in weight matrix
    #pragma unroll
    for (int j = 0; j < 8; ++j) {
      if (w == 0) {
        wfA[t][j] = f2bf(scA * Whh0[ga * HID + 8 * m + j]);
        wfB[t][j] = 0;
      } else {
        wfA[t][j] = f2bf(scA * Wih1[ga * HID + 8 * m + j]);
        wfB[t][j] = f2bf(scA * Whh1[ga * HID + 8 * m + j]);
      }
    }
    const int u = 8 * m + t;               // owned cell unit (tile t)
    #pragma unroll
    for (int r = 0; r < 4; ++r) {
      const float sc = (r == 2) ? (2.0f * L2E) : (-L2E);
      cb[t][r]  = sc * (Bi[r * 32 + u] + Bh[r * 32 + u]);
      w0x[t][r] = (w == 0) ? sc * Wih0[r * 32 + u] : 0.f;
    }
    wfc[t] = (w == 1) ? Wfc[u] : 0.f;
  }

  bf16x8 hf = {};                 // own h fragment (h0 for w0, h1 for w1)
  float cv[8], hh[8];
  #pragma unroll
  for (int t = 0; t < 8; ++t) { cv[t] = 0.f; hh[t] = 0.f; }

  const float* xb = x + (size_t)batch * SEQ;
  const int wrd = col * LSTR + 4 * m;      // ring b128 slot (dwords)

  float4 xcur = {0.f, 0.f, 0.f, 0.f};
  if (w == 0) xcur = *reinterpret_cast<const float4*>(xb);

  for (int k = 0; k <= SEQ / 4; ++k) {
    if (w == 0 && k < SEQ / 4) {
      // ---- producer: steps 4k..4k+3 of layer 0, all in-register ----
      float4 xnext = {0.f, 0.f, 0.f, 0.f};
      if (k + 1 < SEQ / 4)
        xnext = *reinterpret_cast<const float4*>(xb + (k + 1) * 4);
      #pragma unroll
      for (int uu = 0; uu < 4; ++uu) {
        const float xt = (uu == 0) ? xcur.x : (uu == 1) ? xcur.y
                       : (uu == 2) ? xcur.z : xcur.w;
        f32x4 A[8];
        #pragma unroll
        for (int t = 0; t < 8; ++t) {
          f32x4 cbx;
          #pragma unroll
          for (int r = 0; r < 4; ++r) cbx[r] = fmaf(w0x[t][r], xt, cb[t][r]);
          A[t] = __builtin_amdgcn_mfma_f32_16x16x32_bf16(wfA[t], hf, cbx, 0, 0, 0);
        }
        #pragma unroll
        for (int t = 0; t < 8; ++t)   // D regs ARE (i,f,g,o) of unit 8m+t
          CELL(A[t][0], A[t][1], A[t][2], A[t][3], cv[t], hh[t]);
        i32x4 pk;
        #pragma unroll
        for (int j2 = 0; j2 < 4; ++j2) {
          int p;
          asm("v_cvt_pk_bf16_f32 %0, %1, %2"
              : "=v"(p) : "v"(hh[2 * j2]), "v"(hh[2 * j2 + 1]));
          pk[j2] = p;
        }
        hf = __builtin_bit_cast(bf16x8, pk);      // next-step B-frag, in-lane
        *(i32x4*)&ring[(4 * k + uu) & 7][wrd] = pk;  // publish h0 for w1
      }
      xcur = xnext;
    }
    if (w == 1 && k > 0) {
      // ---- consumer: steps 4(k-1)..4(k-1)+3 of layer 1 (lag 4..7) ----
      i32x4 h0v[4];
      #pragma unroll
      for (int uu = 0; uu < 4; ++uu)   // prefetch all 4 (written >=1 barrier ago)
        h0v[uu] = *(const i32x4*)&ring[(4 * (k - 1) + uu) & 7][wrd];
      #pragma unroll
      for (int uu = 0; uu < 4; ++uu) {
        const bf16x8 h0f = __builtin_bit_cast(bf16x8, h0v[uu]);
        f32x4 A[8];
        #pragma unroll
        for (int t = 0; t < 8; ++t)    // Wih1*h0 + bias (h1-independent, first)
          A[t] = __builtin_amdgcn_mfma_f32_16x16x32_bf16(wfA[t], h0f, cb[t], 0, 0, 0);
        #pragma unroll
        for (int t = 0; t < 8; ++t)    // + Whh1*h1 (fresh recurrent, last)
          A[t] = __builtin_amdgcn_mfma_f32_16x16x32_bf16(wfB[t], hf, A[t], 0, 0, 0);
        #pragma unroll
        for (int t = 0; t < 8; ++t)
          CELL(A[t][0], A[t][1], A[t][2], A[t][3], cv[t], hh[t]);
        i32x4 pk;
        #pragma unroll
        for (int j2 = 0; j2 < 4; ++j2) {
          int p;
          asm("v_cvt_pk_bf16_f32 %0, %1, %2"
              : "=v"(p) : "v"(hh[2 * j2]), "v"(hh[2 * j2 + 1]));
          pk[j2] = p;
        }
        hf = __builtin_bit_cast(bf16x8, pk);      // h1 B-frag stays in-lane
      }
    }
    __syncthreads();   // one barrier per 4 steps (ring slots stay disjoint)
  }

  // ---- FC + ReLU: w1 holds h1(511) units 8m..8m+7 in hh ----
  if (w == 1) {
    float part = 0.f;
    #pragma unroll
    for (int t = 0; t < 8; ++t) part = fmaf(hh[t], wfc[t], part);
    part += __shfl_xor(part, 16);   // reduce over m (k-groups)
    part += __shfl_xor(part, 32);
    if (l < 16) {
      const float o = part + bfc[0];
      out[blockIdx.x * 16 + l] = o > 0.f ? o : 0.f;
    }
  }
}

extern "C" void kernel_launch(void* const* d_in, const int* in_sizes, int n_in,
                              void* d_out, int out_size, void* d_ws, size_t ws_size,
                              hipStream_t stream) {
  const float* x    = (const float*)d_in[0];
  const float* Wih0 = (const float*)d_in[1];
  const float* Whh0 = (const float*)d_in[2];
  const float* bih0 = (const float*)d_in[3];
  const float* bhh0 = (const float*)d_in[4];
  const float* Wih1 = (const float*)d_in[5];
  const float* Whh1 = (const float*)d_in[6];
  const float* bih1 = (const float*)d_in[7];
  const float* bhh1 = (const float*)d_in[8];
  const float* Wfc  = (const float*)d_in[9];
  const float* bfc  = (const float*)d_in[10];

  const int B = 4096;
  const int grid = B / 16;   // 256 blocks x 2 waves -> 1 block/CU
  lstm2_sa_kernel<<<grid, 128, 0, stream>>>(
      x, Wih0, Whh0, bih0, bhh0, Wih1, Whh1, bih1, bhh1, Wfc, bfc,
      (float*)d_out);
}

// Round 19
// 179.101 us; speedup vs baseline: 2.0619x; 2.0619x over previous
//
#include <hip/hip_runtime.h>
#include <hip/hip_bf16.h>

// 2-layer LSTM (H=32, T=512, I=1) + FC(1) + ReLU, fused, ZERO-SELECT
// 8-wave unit-split, 16 batches/block (R15/R16 champion structure).
// NEW vs R16: WAVE-ROLE PRIORITY INVERSION. The block's binding dependency
// chain is L0's 1-step recurrence (h0(i)->h0(i+1)); L1 lags 2 steps with a
// 4-parity ring (1-2 steps of slack). R15/16 transiently boosted L1's
// MFMAs -- backwards. Now: persistent s_setprio(1) for the 4 L0 waves,
// L1 stays prio 0 (transient toggles removed). Issue arbitration between
// co-resident waves stops inflating the critical chain.
// Everything else identical to R16: adjacent-unit tiles (lane m owns units
// 8V+2m,+1 -> h-publish = 1 cvt_pk + 1 ds_write_b32), L1 lag-2 with h0
// register prefetch, bias+x folded into MFMA C-in, parallel P/Q L1 MFMAs,
// merged-rcp CELL (7 trans), one __syncthreads per step, pre-zeroed LDS.
// 256 blocks x 8 waves = 2048 waves = 2/SIMD.

typedef __attribute__((ext_vector_type(8))) short bf16x8;
typedef __attribute__((ext_vector_type(4))) float f32x4;
typedef __attribute__((ext_vector_type(4))) int   i32x4;

#define HID 32
#define SEQ 512
#define L2E 1.4426950408889634f
#define LSTR 20   // LDS h-row stride in dwords (16 used + 4 pad, 16B-aligned)

static __device__ __forceinline__ float fexp2(float x){ return __builtin_amdgcn_exp2f(x); }
static __device__ __forceinline__ float frcp (float x){ return __builtin_amdgcn_rcpf(x); }
static __device__ __forceinline__ short f2bf(float f){
  unsigned u = __builtin_bit_cast(unsigned, f);
  u = (u + 0x7fffu + ((u >> 16) & 1u)) >> 16;
  return (short)u;
}

// fused LSTM cell, merged-rcp form. Gates pre-scaled (i,f,o by -log2e;
// g by +2log2e):  I=e^-i, F=e^-f, O=e^-o, G=e^{2g}.
#define CELL(gi, gf, gg, go, cvr, hout) do {                         \
  const float I_ = fexp2(gi), G_ = fexp2(gg);                        \
  const float F_ = fexp2(gf), O_ = fexp2(go);                        \
  const float a_ = 1.f + I_, b_ = 1.f + G_, c_ = 1.f + F_;           \
  const float P1_ = a_ * b_;                                         \
  const float R_  = frcp(c_ * P1_);                                  \
  const float fv_ = P1_ * R_;                                        \
  const float ig_ = (G_ - 1.f) * (c_ * R_);                          \
  (cvr) = fmaf(fv_, (cvr), ig_);                                     \
  const float C2_ = fexp2((cvr) * (2.f * L2E));                      \
  (hout) = (C2_ - 1.f) * frcp((1.f + O_) * (1.f + C2_));             \
} while (0)

__global__ __launch_bounds__(512, 2) void lstm2_zs4_kernel(
    const float* __restrict__ x,
    const float* __restrict__ Wih0, const float* __restrict__ Whh0,
    const float* __restrict__ bih0, const float* __restrict__ bhh0,
    const float* __restrict__ Wih1, const float* __restrict__ Whh1,
    const float* __restrict__ bih1, const float* __restrict__ bhh1,
    const float* __restrict__ Wfc, const float* __restrict__ bfc,
    float* __restrict__ out)
{
  const int tid = threadIdx.x;
  const int w   = tid >> 6;          // 0-3: L0 groups; 4-7: L1 groups
  const int l   = tid & 63;
  const int m   = l >> 4;            // k-group; owns units 8V+2m, 8V+2m+1
  const int col = l & 15;            // batch slot (16 batches/block)
  const int V   = w & 3;             // unit group: units 8V..8V+7
  const bool isL1 = (w >= 4);

  __shared__ int   bufH0[4][16 * LSTR];   // 4 parities (lag-2 prefetch)
  __shared__ int   bufH1[2][16 * LSTR];
  __shared__ float bufFC[4][16];

  // zero-init exchange buffers (kills all t=0 special cases)
  for (int i = tid; i < 4 * 16 * LSTR; i += 512) ((int*)bufH0)[i] = 0;
  for (int i = tid; i < 2 * 16 * LSTR; i += 512) ((int*)bufH1)[i] = 0;
  __syncthreads();

  // ---- weights: tile t row rho = gate(rho&3) of unit 8V+2*(rho>>2)+t.
  //      Lane supplies A row = col. Pre-scaled: i,f,o -> -log2e; g -> +2log2e.
  const float* Wrec = isL1 ? Whh1 : Whh0;
  const float* Bi   = isL1 ? bih1 : bih0;
  const float* Bh   = isL1 ? bhh1 : bhh0;
  const int   gcol  = col & 3;             // gate type this lane's A-row feeds
  const float scA   = (gcol == 2) ? (2.0f * L2E) : (-L2E);
  bf16x8 wfR[2], wfI[2];
  f32x4  cb[2];
  float  w0x[2][4];
  #pragma unroll
  for (int t = 0; t < 2; ++t) {
    const int ga = gcol * 32 + 8 * V + 2 * (col >> 2) + t;  // A-row unit's gate row
    #pragma unroll
    for (int j = 0; j < 8; ++j) {
      wfR[t][j] = f2bf(scA * Wrec[ga * HID + (8 * m + j)]);
      wfI[t][j] = isL1 ? f2bf(scA * Wih1[ga * HID + (8 * m + j)]) : (short)0;
    }
    const int uc = 8 * V + 2 * m + t;            // owned cell unit (tile t)
    #pragma unroll
    for (int rr = 0; rr < 4; ++rr) {
      const float sc = (rr == 2) ? (2.0f * L2E) : (-L2E);
      cb[t][rr]  = sc * (Bi[rr * 32 + uc] + Bh[rr * 32 + uc]);
      w0x[t][rr] = isL1 ? 0.f : sc * Wih0[rr * 32 + uc];
    }
  }
  const float wfcA = isL1 ? Wfc[8 * V + 2 * m]     : 0.f;
  const float wfcB = isL1 ? Wfc[8 * V + 2 * m + 1] : 0.f;

  // ---- PRIORITY INVERSION: L0 waves carry the block's 1-step critical
  //      chain; give them persistent issue priority. L1 (2-step slack)
  //      stays at 0 and fills L0's latency gaps.
  if (!isL1) __builtin_amdgcn_s_setprio(1);

  float cvA = 0.f, cvB = 0.f, hA = 0.f, hB = 0.f;
  i32x4 h0pre = {0, 0, 0, 0};        // L1: h0(i-2) register prefetch
  const float* xb = x + (size_t)(blockIdx.x * 16 + col) * SEQ;
  const int  rd = col * LSTR + 4 * m;            // b128 read: units 8m..8m+7
  const int  wb = col * LSTR + 4 * V + m;        // b32 write: own unit pair

  float4 xcur = {0.f, 0.f, 0.f, 0.f};
  if (!isL1) xcur = *reinterpret_cast<const float4*>(xb);   // k = 0

  for (int k = 0; k < SEQ / 4; ++k) {
    float4 xnext = {0.f, 0.f, 0.f, 0.f};
    if (!isL1 && k + 1 < SEQ / 4)
      xnext = *reinterpret_cast<const float4*>(xb + (k + 1) * 4);  // prefetch
    #pragma unroll
    for (int uu = 0; uu < 4; ++uu) {
      if (!isL1) {
        // ---- L0: h0(i) from h0(i-1) in bufH0[(i-1)&3] ----
        const i32x4 hv = *(const i32x4*)&bufH0[(uu + 3) & 3][rd];
        const bf16x8 hf = __builtin_bit_cast(bf16x8, hv);
        const float xt = (uu == 0) ? xcur.x : (uu == 1) ? xcur.y
                       : (uu == 2) ? xcur.z : xcur.w;
        // bias + x folded into C-in (computes while LDS read is in flight)
        f32x4 cbx0, cbx1;
        #pragma unroll
        for (int rr = 0; rr < 4; ++rr) {
          cbx0[rr] = fmaf(w0x[0][rr], xt, cb[0][rr]);
          cbx1[rr] = fmaf(w0x[1][rr], xt, cb[1][rr]);
        }
        f32x4 A0, A1;
        A0 = __builtin_amdgcn_mfma_f32_16x16x32_bf16(wfR[0], hf, cbx0, 0, 0, 0);
        A1 = __builtin_amdgcn_mfma_f32_16x16x32_bf16(wfR[1], hf, cbx1, 0, 0, 0);
        // regs ARE (i,f,g,o) of the owned units -- zero select
        CELL(A0[0], A0[1], A0[2], A0[3], cvA, hA);
        CELL(A1[0], A1[1], A1[2], A1[3], cvB, hB);
        int pk;
        asm("v_cvt_pk_bf16_f32 %0, %1, %2" : "=v"(pk) : "v"(hA), "v"(hB));
        bufH0[uu][wb] = pk;            // units (8V+2m, 8V+2m+1) = pair 4V+m
      } else {
        const bool doC = (uu >= 2) || (k > 0);   // compute h1(i-2)
        const bool doP = (uu >= 1) || (k > 0);   // prefetch h0(i-1)
        i32x4 h1v = {0, 0, 0, 0};
        if (doC) h1v = *(const i32x4*)&bufH1[(uu + 1) & 1][rd];  // h1(i-3)
        i32x4 h0next = h0pre;
        if (doP) h0next = *(const i32x4*)&bufH0[(uu + 3) & 3][rd]; // h0(i-1)
        if (doC) {
          const bf16x8 h0f = __builtin_bit_cast(bf16x8, h0pre);
          const bf16x8 h1f = __builtin_bit_cast(bf16x8, h1v);
          const f32x4 z4 = {0.f, 0.f, 0.f, 0.f};
          f32x4 P0, P1, Q0, Q1;
          P0 = __builtin_amdgcn_mfma_f32_16x16x32_bf16(wfI[0], h0f, cb[0], 0, 0, 0);
          P1 = __builtin_amdgcn_mfma_f32_16x16x32_bf16(wfI[1], h0f, cb[1], 0, 0, 0);
          Q0 = __builtin_amdgcn_mfma_f32_16x16x32_bf16(wfR[0], h1f, z4, 0, 0, 0);
          Q1 = __builtin_amdgcn_mfma_f32_16x16x32_bf16(wfR[1], h1f, z4, 0, 0, 0);
          const f32x4 A0 = P0 + Q0;     // independent MFMAs complete in
          const f32x4 A1 = P1 + Q1;     // parallel; merge with v_add
          CELL(A0[0], A0[1], A0[2], A0[3], cvA, hA);
          CELL(A1[0], A1[1], A1[2], A1[3], cvB, hB);
          int pk;
          asm("v_cvt_pk_bf16_f32 %0, %1, %2" : "=v"(pk) : "v"(hA), "v"(hB));
          bufH1[uu & 1][wb] = pk;      // h1(i-2) -> slot (i-2)&1 = i&1
        }
        h0pre = h0next;
      }
      __syncthreads();
    }
    xcur = xnext;
  }

  // ---- epilogue: L1 still owes h1(510), h1(511) ----
  if (isL1) {
    // h1(510) = f(h0(510)=h0pre, h1(509)=bufH1[1])
    const i32x4 h1v = *(const i32x4*)&bufH1[1][rd];
    const bf16x8 h0f = __builtin_bit_cast(bf16x8, h0pre);
    const bf16x8 h1f = __builtin_bit_cast(bf16x8, h1v);
    f32x4 A0, A1;
    A0 = __builtin_amdgcn_mfma_f32_16x16x32_bf16(wfI[0], h0f, cb[0], 0, 0, 0);
    A1 = __builtin_amdgcn_mfma_f32_16x16x32_bf16(wfI[1], h0f, cb[1], 0, 0, 0);
    A0 = __builtin_amdgcn_mfma_f32_16x16x32_bf16(wfR[0], h1f, A0, 0, 0, 0);
    A1 = __builtin_amdgcn_mfma_f32_16x16x32_bf16(wfR[1], h1f, A1, 0, 0, 0);
    CELL(A0[0], A0[1], A0[2], A0[3], cvA, hA);
    CELL(A1[0], A1[1], A1[2], A1[3], cvB, hB);
    int pk;
    asm("v_cvt_pk_bf16_f32 %0, %1, %2" : "=v"(pk) : "v"(hA), "v"(hB));
    bufH1[0][wb] = pk;                 // h1(510)
  }
  __syncthreads();
  if (isL1) {
    // h1(511) = f(h0(511)=bufH0[3], h1(510)=bufH1[0]); then FC partial
    const i32x4 h0v = *(const i32x4*)&bufH0[3][rd];
    const i32x4 h1v = *(const i32x4*)&bufH1[0][rd];
    const bf16x8 h0f = __builtin_bit_cast(bf16x8, h0v);
    const bf16x8 h1f = __builtin_bit_cast(bf16x8, h1v);
    f32x4 A0, A1;
    A0 = __builtin_amdgcn_mfma_f32_16x16x32_bf16(wfI[0], h0f, cb[0], 0, 0, 0);
    A1 = __builtin_amdgcn_mfma_f32_16x16x32_bf16(wfI[1], h0f, cb[1], 0, 0, 0);
    A0 = __builtin_amdgcn_mfma_f32_16x16x32_bf16(wfR[0], h1f, A0, 0, 0, 0);
    A1 = __builtin_amdgcn_mfma_f32_16x16x32_bf16(wfR[1], h1f, A1, 0, 0, 0);
    CELL(A0[0], A0[1], A0[2], A0[3], cvA, hA);
    CELL(A1[0], A1[1], A1[2], A1[3], cvB, hB);
    float part = hA * wfcA + hB * wfcB;
    part += __shfl_xor(part, 16);   // sum over m
    part += __shfl_xor(part, 32);
    if (l < 16) bufFC[V][l] = part;  // l<16 -> m==0, col=l
  }
  __syncthreads();
  if (w == 4 && l < 16) {
    const float o = bufFC[0][l] + bufFC[1][l] + bufFC[2][l] + bufFC[3][l] + bfc[0];
    out[blockIdx.x * 16 + l] = o > 0.f ? o : 0.f;
  }
}

extern "C" void kernel_launch(void* const* d_in, const int* in_sizes, int n_in,
                              void* d_out, int out_size, void* d_ws, size_t ws_size,
                              hipStream_t stream) {
  const float* x    = (const float*)d_in[0];
  const float* Wih0 = (const float*)d_in[1];
  const float* Whh0 = (const float*)d_in[2];
  const float* bih0 = (const float*)d_in[3];
  const float* bhh0 = (const float*)d_in[4];
  const float* Wih1 = (const float*)d_in[5];
  const float* Whh1 = (const float*)d_in[6];
  const float* bih1 = (const float*)d_in[7];
  const float* bhh1 = (const float*)d_in[8];
  const float* Wfc  = (const float*)d_in[9];
  const float* bfc  = (const float*)d_in[10];

  const int B = 4096;
  const int grid = B / 16;   // 256 blocks x 8 waves = 2048 waves -> 2/SIMD
  lstm2_zs4_kernel<<<grid, 512, 0, stream>>>(
      x, Wih0, Whh0, bih0, bhh0, Wih1, Whh1, bih1, bhh1, Wfc, bfc,
      (float*)d_out);
}